// Round 1
// baseline (1814.292 us; speedup 1.0000x reference)
//
#include <hip/hip_runtime.h>
#include <math.h>

#define N_PTS 8192
#define M_PTS 2048
#define KLAST 10
#define VARS 3
#define IND 8
#define PH 64
#define OUTD 32
#define D1 80
#define D2 80
#define AGGD 36

__device__ __forceinline__ float gelu_f(float x) {
    // exact gelu: x * Phi(x)
    return 0.5f * x * (1.0f + erff(x * 0.70710678118654752f));
}

// ---------------- projection: (N,3,8) -> gelu(@W0)+... -> f0[(v*N+n)*32+c] ----
__global__ __launch_bounds__(64) void proj_kernel(
    const float* __restrict__ inp,
    const float* __restrict__ W0, const float* __restrict__ b0,
    const float* __restrict__ W1, const float* __restrict__ b1,
    float* __restrict__ f0)
{
    int row = blockIdx.x;            // [0, N*VARS)
    int n = row / VARS, v = row % VARS;
    int t = threadIdx.x;             // 64 threads = PH
    __shared__ float xs[IND];
    __shared__ float h[PH];
    if (t < IND) xs[t] = inp[n * (VARS * IND) + v * IND + t];
    __syncthreads();
    float s = b0[t];
#pragma unroll
    for (int k = 0; k < IND; ++k) s += xs[k] * W0[k * PH + t];
    h[t] = gelu_f(s);
    __syncthreads();
    if (t < OUTD) {
        float o = b1[t];
#pragma unroll
        for (int k = 0; k < PH; ++k) o += h[k] * W1[k * OUTD + t];
        f0[(v * N_PTS + n) * OUTD + t] = o;
    }
}

// ---------------- exclusive scan of counts (8192) -> offsets -----------------
__global__ __launch_bounds__(1024) void scan_kernel(
    const int* __restrict__ counts, int* __restrict__ offsets)
{
    __shared__ int buf[1024];
    __shared__ int carry;
    int t = threadIdx.x;
    if (t == 0) carry = 0;
    __syncthreads();
    for (int c = 0; c < N_PTS; c += 1024) {
        int vin = counts[c + t];
        buf[t] = vin;
        __syncthreads();
        for (int off = 1; off < 1024; off <<= 1) {
            int val = (t >= off) ? buf[t - off] : 0;
            __syncthreads();
            buf[t] += val;
            __syncthreads();
        }
        int incl = buf[t];
        offsets[c + t] = carry + incl - vin;   // exclusive
        __syncthreads();
        if (t == 1023) carry += incl;
        __syncthreads();
    }
}

// ---------------- per-target edge MLP + segment mean -------------------------
// block = one target point i; loops vars; edges in tiles of 32
__global__ __launch_bounds__(256) void agg_kernel(
    const float* __restrict__ grid_in,
    const float* __restrict__ f0,
    const int* __restrict__ nbr_index,
    const int* __restrict__ nbr_counts,
    const int* __restrict__ offsets,
    const float* __restrict__ W0, const float* __restrict__ b0,
    const float* __restrict__ W1, const float* __restrict__ b1,
    const float* __restrict__ W2, const float* __restrict__ b2,
    float* __restrict__ f1)
{
    __shared__ float W1s[D1 * D2];      // 25.6 KB
    __shared__ float W2s[D2 * OUTD];    // 10.2 KB
    __shared__ float b0s[D1], b1s[D2], b2s[OUTD];
    __shared__ float bufA[32 * D1];     // agg (pitch 37) then H2 (pitch 80)
    __shared__ float bufB[32 * D1];     // H1 (pitch 80) then out (pitch 33)
    __shared__ int   jb[32];
    __shared__ float accv[OUTD];

    int i = blockIdx.x;
    int t = threadIdx.x;

    for (int idx = t; idx < D1 * D2; idx += 256) W1s[idx] = W1[idx];
    for (int idx = t; idx < D2 * OUTD; idx += 256) W2s[idx] = W2[idx];
    if (t < D1) b0s[t] = b0[t];
    if (t < D2) b1s[t] = b1[t];
    if (t < OUTD) b2s[t] = b2[t];

    int cnt = nbr_counts[i];
    int start = offsets[i];
    float inv = 1.0f / (float)(cnt > 1 ? cnt : 1);
    float sx = grid_in[i * 2 + 0], sy = grid_in[i * 2 + 1];
    __syncthreads();

    for (int v = 0; v < VARS; ++v) {
        if (t < OUTD) accv[t] = 0.0f;
        for (int ts = 0; ts < cnt; ts += 32) {
            int te = min(32, cnt - ts);
            __syncthreads();
            if (t < te) jb[t] = nbr_index[start + ts + t];
            __syncthreads();
            // stage agg rows [grid[j], grid[i], f0[v][j]] into bufA pitch 37
            for (int idx = t; idx < te * AGGD; idx += 256) {
                int e = idx / AGGD, k = idx - e * AGGD;
                int j = jb[e];
                float val;
                if (k < 4) val = (k < 2) ? grid_in[j * 2 + k] : ((k == 2) ? sx : sy);
                else       val = f0[(v * N_PTS + j) * OUTD + (k - 4)];
                bufA[e * 37 + k] = val;
            }
            __syncthreads();
            // layer1: H1 = gelu(agg @ W0 + b0) -> bufB pitch 80
            for (int idx = t; idx < te * D1; idx += 256) {
                int e = idx / D1, hh = idx - e * D1;
                float s = b0s[hh];
#pragma unroll
                for (int k = 0; k < AGGD; ++k) s += bufA[e * 37 + k] * W0[k * D1 + hh];
                bufB[e * D1 + hh] = gelu_f(s);
            }
            __syncthreads();
            // layer2: H2 = gelu(H1 @ W1 + b1) -> bufA pitch 80
            for (int idx = t; idx < te * D2; idx += 256) {
                int e = idx / D2, hh = idx - e * D2;
                float s = b1s[hh];
#pragma unroll 4
                for (int k = 0; k < D1; ++k) s += bufB[e * D1 + k] * W1s[k * D2 + hh];
                bufA[e * D2 + hh] = gelu_f(s);
            }
            __syncthreads();
            // layer3: out = H2 @ W2 + b2 -> bufB pitch 33
            for (int idx = t; idx < te * OUTD; idx += 256) {
                int e = idx / OUTD, c = idx - e * OUTD;
                float s = b2s[c];
#pragma unroll 4
                for (int k = 0; k < D2; ++k) s += bufA[e * D2 + k] * W2s[k * OUTD + c];
                bufB[e * 33 + c] = s;
            }
            __syncthreads();
            if (t < OUTD) {
                float s = 0.0f;
                for (int e = 0; e < te; ++e) s += bufB[e * 33 + t];
                accv[t] += s;
            }
        }
        __syncthreads();
        if (t < OUTD) {
            int o = (v * N_PTS + i) * OUTD + t;
            f1[o] = accv[t] * inv + f0[o];
        }
        __syncthreads();
    }
}

// ---------------- kNN interpolation MLP + mean over K ------------------------
// block = one output point m; 30 rows = 3 vars x 10 knn
__global__ __launch_bounds__(256) void last_kernel(
    const float* __restrict__ grid_in,
    const float* __restrict__ grid_out,
    const float* __restrict__ f1,
    const int* __restrict__ nbr_last,
    const float* __restrict__ W0, const float* __restrict__ b0,
    const float* __restrict__ W1, const float* __restrict__ b1,
    const float* __restrict__ W2, const float* __restrict__ b2,
    float* __restrict__ out)
{
    __shared__ float W1s[D1 * D2];
    __shared__ float W2s[D2 * OUTD];
    __shared__ float b0s[D1], b1s[D2], b2s[OUTD];
    __shared__ float bufA[30 * D1];
    __shared__ float bufB[30 * D1];
    __shared__ int   jb[KLAST];

    int m = blockIdx.x;
    int t = threadIdx.x;
    for (int idx = t; idx < D1 * D2; idx += 256) W1s[idx] = W1[idx];
    for (int idx = t; idx < D2 * OUTD; idx += 256) W2s[idx] = W2[idx];
    if (t < D1) b0s[t] = b0[t];
    if (t < D2) b1s[t] = b1[t];
    if (t < OUTD) b2s[t] = b2[t];
    if (t < KLAST) jb[t] = nbr_last[m * KLAST + t];
    float sx = grid_out[m * 2 + 0], sy = grid_out[m * 2 + 1];
    __syncthreads();

    const int R = VARS * KLAST;  // 30
    for (int idx = t; idx < R * AGGD; idx += 256) {
        int r = idx / AGGD, k = idx - r * AGGD;
        int v = r / KLAST, kk = r - v * KLAST;
        int j = jb[kk];
        float val;
        if (k < 4) val = (k < 2) ? grid_in[j * 2 + k] : ((k == 2) ? sx : sy);
        else       val = f1[(v * N_PTS + j) * OUTD + (k - 4)];
        bufA[r * 37 + k] = val;
    }
    __syncthreads();
    for (int idx = t; idx < R * D1; idx += 256) {
        int r = idx / D1, hh = idx - r * D1;
        float s = b0s[hh];
#pragma unroll
        for (int k = 0; k < AGGD; ++k) s += bufA[r * 37 + k] * W0[k * D1 + hh];
        bufB[r * D1 + hh] = gelu_f(s);
    }
    __syncthreads();
    for (int idx = t; idx < R * D2; idx += 256) {
        int r = idx / D2, hh = idx - r * D2;
        float s = b1s[hh];
#pragma unroll 4
        for (int k = 0; k < D1; ++k) s += bufB[r * D1 + k] * W1s[k * D2 + hh];
        bufA[r * D2 + hh] = gelu_f(s);
    }
    __syncthreads();
    for (int idx = t; idx < R * OUTD; idx += 256) {
        int r = idx / OUTD, c = idx - r * OUTD;
        float s = b2s[c];
#pragma unroll 4
        for (int k = 0; k < D2; ++k) s += bufA[r * D2 + k] * W2s[k * OUTD + c];
        bufB[r * 33 + c] = s;
    }
    __syncthreads();
    if (t < VARS * OUTD) {
        int v = t / OUTD, c = t - v * OUTD;
        float s = 0.0f;
#pragma unroll
        for (int k = 0; k < KLAST; ++k) s += bufB[(v * KLAST + k) * 33 + c];
        out[m * (VARS * OUTD) + t] = s * (1.0f / KLAST);
    }
}

extern "C" void kernel_launch(void* const* d_in, const int* in_sizes, int n_in,
                              void* d_out, int out_size, void* d_ws, size_t ws_size,
                              hipStream_t stream) {
    const float* inp      = (const float*)d_in[0];
    const float* grid_in  = (const float*)d_in[1];
    const float* grid_out = (const float*)d_in[2];
    const float* pW0 = (const float*)d_in[3];
    const float* pb0 = (const float*)d_in[4];
    const float* pW1 = (const float*)d_in[5];
    const float* pb1 = (const float*)d_in[6];
    const float* i0W0 = (const float*)d_in[7];
    const float* i0b0 = (const float*)d_in[8];
    const float* i0W1 = (const float*)d_in[9];
    const float* i0b1 = (const float*)d_in[10];
    const float* i0W2 = (const float*)d_in[11];
    const float* i0b2 = (const float*)d_in[12];
    const float* i1W0 = (const float*)d_in[13];
    const float* i1b0 = (const float*)d_in[14];
    const float* i1W1 = (const float*)d_in[15];
    const float* i1b1 = (const float*)d_in[16];
    const float* i1W2 = (const float*)d_in[17];
    const float* i1b2 = (const float*)d_in[18];
    const int* nbr_index  = (const int*)d_in[19];
    const int* nbr_counts = (const int*)d_in[21];
    const int* nbr_last   = (const int*)d_in[22];

    float* f0 = (float*)d_ws;                                  // V*N*32
    float* f1 = f0 + (size_t)VARS * N_PTS * OUTD;              // V*N*32
    int* offsets = (int*)(f1 + (size_t)VARS * N_PTS * OUTD);   // N

    proj_kernel<<<N_PTS * VARS, 64, 0, stream>>>(inp, pW0, pb0, pW1, pb1, f0);
    scan_kernel<<<1, 1024, 0, stream>>>(nbr_counts, offsets);
    agg_kernel<<<N_PTS, 256, 0, stream>>>(grid_in, f0, nbr_index, nbr_counts, offsets,
                                          i0W0, i0b0, i0W1, i0b1, i0W2, i0b2, f1);
    last_kernel<<<M_PTS, 256, 0, stream>>>(grid_in, grid_out, f1, nbr_last,
                                           i1W0, i1b0, i1W1, i1b1, i1W2, i1b2,
                                           (float*)d_out);
}